// Round 5
// baseline (351.970 us; speedup 1.0000x reference)
//
#include <hip/hip_runtime.h>
#include <cstdint>
#include <cstddef>

// Problem dims
#define B_ROWS 65536
#define D_IN   784
#define KP     800      // D_IN padded to multiple of 32
#define D_H    300
#define NP     320      // D_H padded to multiple of 64
#define D_OUT  10
#define NP2    16       // D_OUT padded to 16
#define EPS    1e-5f
#define APAD   40       // LDS A row stride in halfs (80 B: 16B-aligned, 2-way banks = free)

typedef _Float16 half8  __attribute__((ext_vector_type(8)));
typedef float    floatx4 __attribute__((ext_vector_type(4)));

// Workspace layout (bytes). part[] aliases oc[]: part is consumed by k_statfold
// BEFORE k_gemm2 writes oc (strictly ordered on one stream).
#define OFF_S1   ((size_t)0)                       // _Float16[320*800]   = 512000
#define OFF_H    ((size_t)512000)                  // _Float16[65536*320] = 41943040
#define OFF_W2   (OFF_H + (size_t)41943040)        // _Float16[16*320]    = 10240
#define OFF_ST2  (OFF_W2 + (size_t)10240)          // float[32]
#define OFF_OC   (OFF_ST2 + (size_t)256)           // float[65536*16]     = 4194304
#define OFF_P1   OFF_OC                            // float[640][1024] (alias, time-disjoint)
#define OFF_P2   (OFF_OC + (size_t)4194304)        // float[32][1024]     = 131072

// ---------------- K0: binarize W1 -> fp16 (+-1), zero-padded to [320][800]
__global__ void k_prep1(const float* __restrict__ W1, _Float16* __restrict__ S1)
{
    int idx = blockIdx.x * 256 + threadIdx.x;      // 0..255999
    int n = idx / KP;
    int k = idx - n * KP;
    float v = 0.0f;
    if (n < D_H && k < D_IN)
        v = (W1[n * D_IN + k] >= 0.0f) ? 1.0f : -1.0f;
    S1[idx] = (_Float16)v;
}

// ---------------- K1: h = x @ S1^T  (M=65536, N=320, K=800), fp16 MFMA
// 512 thr (8 waves: 2 row-halves x 4 col-quarters), tile 128 x 320 (full N ->
// x read once from HBM). RAW s_barrier pipeline (no vmcnt(0) drain): LDS A
// ping-pong + TWO named register staging sets (x loaded 2 steps ahead; ~1000+
// cyc slack >= HBM latency since the harness's 784 MiB ws-poison thrashes L3
// every iteration) + B-register ping-pong (L2-resident, 2-step slack).
// Explicit `s_waitcnt lgkmcnt(0)` before each raw s_barrier covers the LDS
// producer->consumer dependency; global loads stay in flight across barriers.

#define LOAD_R(RA, RB, KK)                                                  \
    {                                                                       \
        RA = (floatx4){}; RB = (floatx4){};                                 \
        if ((KK) + sc < D_IN) {            /* chunk-uniform: D_IN%8==0 */   \
            RA = *(const floatx4*)(sxp + (KK));                             \
            RB = *(const floatx4*)(sxp + (KK) + 4);                         \
        }                                                                   \
    }

#define STAGE_WRITE(BUF, RA, RB)                                            \
    {                                                                       \
        half8 hv;                                                           \
        _Pragma("unroll")                                                   \
        for (int i2 = 0; i2 < 4; ++i2) {                                    \
            hv[i2]     = (_Float16)RA[i2];                                  \
            hv[4 + i2] = (_Float16)RB[i2];                                  \
        }                                                                   \
        *(half8*)&Alds[BUF][srow][sc] = hv;                                 \
    }

#define PF_B(BV, NK)                                                        \
    _Pragma("unroll")                                                       \
    for (int nt = 0; nt < 5; ++nt)                                          \
        BV[nt] = *(const half8*)(bb + (size_t)nt * 16 * KP + (NK));

#define AFRAG(BUF)                                                          \
    _Pragma("unroll")                                                       \
    for (int mt = 0; mt < 4; ++mt)                                          \
        a[mt] = *(const half8*)&Alds[BUF][wr * 64 + mt * 16 + row15][quad * 8];

#define COMPUTE(BV)                                                         \
    _Pragma("unroll")                                                       \
    for (int nt = 0; nt < 5; ++nt)                                          \
        _Pragma("unroll")                                                   \
        for (int mt = 0; mt < 4; ++mt)                                      \
            acc[mt][nt] = __builtin_amdgcn_mfma_f32_16x16x32_f16(           \
                a[mt], BV[nt], acc[mt][nt], 0, 0, 0);

#define RAW_BARRIER                                                         \
    asm volatile("s_waitcnt lgkmcnt(0)" ::: "memory");                      \
    asm volatile("s_barrier" ::: "memory");

__global__ __launch_bounds__(512) void k_gemm1(const float* __restrict__ x,
                                               const _Float16* __restrict__ S1,
                                               _Float16* __restrict__ h,
                                               float* __restrict__ part)
{
    __shared__ _Float16 Alds[2][128][APAD];   // 20 KB
    const int t     = threadIdx.x;
    const int wave  = t >> 6;
    const int lane  = t & 63;
    const int row15 = lane & 15;
    const int quad  = lane >> 4;
    const int wr    = wave >> 2;       // row half   (0..1) -> rows wr*64..+64
    const int wc    = wave & 3;        // col quarter(0..3) -> cols wc*80..+80
    const int m0    = blockIdx.x * 128;

    // staging: thread t -> row t>>2 (0..127), float-chunk (t&3)*8
    const int srow = t >> 2;
    const int sc   = (t & 3) * 8;
    const float* sxp = x + (size_t)(m0 + srow) * D_IN + sc;

    // B fragment base (MFMA B layout: lane holds col=row15, k=quad*8..+8)
    const _Float16* bb = S1 + (size_t)(wc * 80 + row15) * KP + quad * 8;

    floatx4 acc[4][5] = {};
    half8   b0[5], b1[5];
    half8   a[4];
    floatx4 r0a, r0b, r1a, r1b;

    // prologue: L0 <- x[k=0]; r1 <- x[32]; r0 <- x[64]; b0 <- B[0]; b1 <- B[32]
    LOAD_R(r0a, r0b, 0)
    STAGE_WRITE(0, r0a, r0b)
    LOAD_R(r1a, r1b, 32)
    LOAD_R(r0a, r0b, 64)
    PF_B(b0, 0)
    PF_B(b1, 32)
    RAW_BARRIER

    for (int i = 0; i < 12; ++i) {
        const int kk = i * 64;
        // even step, K=kk: compute L0/b0; stage L1 <- r1 (x[kk+32])
        AFRAG(0)
        STAGE_WRITE(1, r1a, r1b)
        if (kk + 96 < KP) LOAD_R(r1a, r1b, kk + 96)
        COMPUTE(b0)
        if (kk + 64 < KP) PF_B(b0, kk + 64)
        RAW_BARRIER
        // odd step, K=kk+32: compute L1/b1; stage L0 <- r0 (x[kk+64])
        AFRAG(1)
        STAGE_WRITE(0, r0a, r0b)
        if (kk + 128 < KP) LOAD_R(r0a, r0b, kk + 128)
        COMPUTE(b1)
        if (kk + 96 < KP) PF_B(b1, kk + 96)
        RAW_BARRIER
    }
    // tail step, K=768: L0 (written at step 23), b0 (loaded at step 22)
    AFRAG(0)
    COMPUTE(b0)

    // --- epilogue: store h (C/D layout: col=lane&15, row=quad*4+r) + stats
    float s[5] = {}, q[5] = {};
#pragma unroll
    for (int mt = 0; mt < 4; ++mt)
#pragma unroll
        for (int nt = 0; nt < 5; ++nt)
#pragma unroll
            for (int r = 0; r < 4; ++r) {
                float v = acc[mt][nt][r];
                int m = m0 + wr * 64 + mt * 16 + quad * 4 + r;
                int n = wc * 80 + nt * 16 + row15;
                h[(size_t)m * NP + n] = (_Float16)v;
                s[nt] += v;
                q[nt] += v * v;
            }
    // reduce over quad; col-quarters are disjoint across wc; row-halves (wr)
    // get separate partial slots: slot = blockIdx.x*2 + wr  (1024 slots)
#pragma unroll
    for (int nt = 0; nt < 5; ++nt) {
        s[nt] += __shfl_xor(s[nt], 16); s[nt] += __shfl_xor(s[nt], 32);
        q[nt] += __shfl_xor(q[nt], 16); q[nt] += __shfl_xor(q[nt], 32);
    }
    if (quad == 0) {
        int slot = blockIdx.x * 2 + wr;
#pragma unroll
        for (int nt = 0; nt < 5; ++nt) {
            int col = wc * 80 + nt * 16 + row15;
            part[(size_t)col * 1024 + slot]        = s[nt];
            part[(size_t)(NP + col) * 1024 + slot] = q[nt];
        }
    }
}

// ---------------- K2: reduce layer-1 partials for ONE column + fold BN1 scale
// into binarized W2 -> w2h[16][320] fp16.  Grid: 320 blocks (one per column).
__global__ void k_statfold(const float* __restrict__ part, const float* __restrict__ gamma1,
                           const float* __restrict__ W2, _Float16* __restrict__ w2h)
{
    __shared__ float red[2][4];
    const int j = blockIdx.x;            // column 0..319
    const int t = threadIdx.x;           // 256
    const float* ps = part + (size_t)j * 1024;
    const float* pq = part + (size_t)(NP + j) * 1024;
    float s = ps[t] + ps[t + 256] + ps[t + 512] + ps[t + 768];
    float q = pq[t] + pq[t + 256] + pq[t + 512] + pq[t + 768];
#pragma unroll
    for (int off = 1; off < 64; off <<= 1) {
        s += __shfl_xor(s, off);
        q += __shfl_xor(q, off);
    }
    if ((t & 63) == 0) { red[0][t >> 6] = s; red[1][t >> 6] = q; }
    __syncthreads();
    if (t < NP2) {
        float S = red[0][0] + red[0][1] + red[0][2] + red[0][3];
        float Q = red[1][0] + red[1][1] + red[1][2] + red[1][3];
        float mean = S * (1.0f / 65536.0f);
        float var  = Q * (1.0f / 65536.0f) - mean * mean;
        float w = 0.0f;
        if (t < D_OUT && j < D_H) {
            float a1 = gamma1[j] / sqrtf(var + EPS);
            w = (W2[t * D_H + j] >= 0.0f) ? a1 : -a1;
        }
        w2h[t * NP + j] = (_Float16)w;
    }
}

// ---------------- K3: oc = h @ w2h^T  (K=320, N=16) + per-block stat partials
__global__ __launch_bounds__(256) void k_gemm2(const _Float16* __restrict__ h,
                                               const _Float16* __restrict__ w2h,
                                               float* __restrict__ oc,
                                               float* __restrict__ part2)
{
    __shared__ _Float16 Wlds[16][328];   // pad 320->328 to break bank conflicts
    __shared__ float reds[4][16], redq[4][16];
    const int t     = threadIdx.x;
    const int wave  = t >> 6;
    const int lane  = t & 63;
    const int row15 = lane & 15;
    const int quad  = lane >> 4;

    for (int c = t; c < 640; c += 256) { // 16*320/8 chunks
        int r  = c / 40;
        int cc = (c - r * 40) * 8;
        *(half8*)&Wlds[r][cc] = *(const half8*)(w2h + r * NP + cc);
    }
    __syncthreads();

    const int m0 = blockIdx.x * 64 + wave * 16;
    const _Float16* hp = h + (size_t)(m0 + row15) * NP + quad * 8;
    floatx4 acc = {};
#pragma unroll
    for (int kk = 0; kk < NP; kk += 32) {
        half8 a2 = *(const half8*)(hp + kk);
        half8 b2 = *(const half8*)&Wlds[row15][kk + quad * 8];
        acc = __builtin_amdgcn_mfma_f32_16x16x32_f16(a2, b2, acc, 0, 0, 0);
    }
    float s = 0.f, q = 0.f;
#pragma unroll
    for (int r = 0; r < 4; ++r) {
        float v = acc[r];
        oc[(size_t)(m0 + quad * 4 + r) * NP2 + row15] = v;
        s += v; q += v * v;
    }
    s += __shfl_xor(s, 16); s += __shfl_xor(s, 32);
    q += __shfl_xor(q, 16); q += __shfl_xor(q, 32);
    if (lane < 16) { reds[wave][row15] = s; redq[wave][row15] = q; }
    __syncthreads();
    if (t < 16) {
        float S = reds[0][t] + reds[1][t] + reds[2][t] + reds[3][t];
        float Q = redq[0][t] + redq[1][t] + redq[2][t] + redq[3][t];
        part2[(size_t)t * 1024 + blockIdx.x]        = S;
        part2[(size_t)(16 + t) * 1024 + blockIdx.x] = Q;
    }
}

// ---------------- K4: contention-free reduce of gemm2 partials -> st2[32]
__global__ void k_reduce(const float* __restrict__ part, float* __restrict__ st)
{
    __shared__ float red[4];
    const int c = blockIdx.x;
    const int t = threadIdx.x;           // 256
    const float* p = part + (size_t)c * 1024;
    float s = p[t] + p[t + 256] + p[t + 512] + p[t + 768];
#pragma unroll
    for (int off = 1; off < 64; off <<= 1) s += __shfl_xor(s, off);
    if ((t & 63) == 0) red[t >> 6] = s;
    __syncthreads();
    if (t == 0) st[c] = red[0] + red[1] + red[2] + red[3];
}

// ---------------- K5: BN2 epilogue -> out[65536][10] fp32
__global__ void k_final(const float* __restrict__ oc, const float* __restrict__ st2,
                        const float* __restrict__ gamma2, const float* __restrict__ beta2,
                        float* __restrict__ out)
{
    int idx = blockIdx.x * 256 + threadIdx.x;    // 2560*256 == 655360 exactly
    int m = idx / 10;
    int k = idx - m * 10;
    float mean = st2[k] * (1.0f / 65536.0f);
    float var  = st2[16 + k] * (1.0f / 65536.0f) - mean * mean;
    float sc   = gamma2[k] / sqrtf(var + EPS);
    out[idx] = (oc[(size_t)m * NP2 + k] - mean) * sc + beta2[k];
}

extern "C" void kernel_launch(void* const* d_in, const int* in_sizes, int n_in,
                              void* d_out, int out_size, void* d_ws, size_t ws_size,
                              hipStream_t stream)
{
    const float* x      = (const float*)d_in[0];
    const float* W1     = (const float*)d_in[1];
    const float* gamma1 = (const float*)d_in[2];
    // d_in[3] = beta1 : algebraically cancels under BN2's mean subtraction
    const float* W2     = (const float*)d_in[4];
    const float* gamma2 = (const float*)d_in[5];
    const float* beta2  = (const float*)d_in[6];
    float* out = (float*)d_out;

    char* ws = (char*)d_ws;
    _Float16* S1    = (_Float16*)(ws + OFF_S1);
    _Float16* h     = (_Float16*)(ws + OFF_H);
    _Float16* w2h   = (_Float16*)(ws + OFF_W2);
    float*    st2   = (float*)(ws + OFF_ST2);
    float*    oc    = (float*)(ws + OFF_OC);
    float*    part  = (float*)(ws + OFF_P1);   // aliases oc (time-disjoint)
    float*    part2 = (float*)(ws + OFF_P2);

    k_prep1   <<<1000, 256, 0, stream>>>(W1, S1);
    k_gemm1   <<<512, 512, 0, stream>>>(x, S1, h, part);
    k_statfold<<<320, 256, 0, stream>>>(part, gamma1, W2, w2h);
    k_gemm2   <<<1024, 256, 0, stream>>>(h, w2h, oc, part2);
    k_reduce  <<<32, 256, 0, stream>>>(part2, st2);
    k_final   <<<2560, 256, 0, stream>>>(oc, st2, gamma2, beta2, out);
}